// Round 6
// baseline (124.241 us; speedup 1.0000x reference)
//
#include <hip/hip_runtime.h>
#include <cstdint>

// B=4, L=4096, D=3, VOCAB=8192
#define N_ROWS   16384
#define VOCAB    8192
#define THETA    0.00226f      // compile-time select threshold (~1/8 of codes above)
#define CAP      1536          // sel capacity (expected 1024, +17 sigma safe)
#define THREADS  256           // 4 waves
#define RPW      8             // rows per wave
#define ROWS_PB  32            // 4 waves * 8
#define GRID     (N_ROWS / ROWS_PB)   // 512 blocks

typedef unsigned long long u64;
typedef unsigned int u32;

// d_out (floats): [0,49152) quant_ste | [49152,65536) idx | [65536] vq_loss
// d_ws: [0, GRID*4) float block partials

__global__ __launch_bounds__(THREADS) void vq_main(
    const float* __restrict__ feats, const float* __restrict__ emb,
    float* __restrict__ out_quant, float* __restrict__ out_idx,
    float* __restrict__ part)
{
    __shared__ float4 sSel[CAP];          // (2e0,2e1,2e2,ee) of selected codes
    __shared__ u32    sOrd[CAP];          // original code index
    __shared__ float  sCmax[VOCAB / 16];  // per natural chunk: max nonsel/dropped ee
    __shared__ u32    sCnt;
    __shared__ float  wsum[4];

    const int t = threadIdx.x, lane = t & 63, wave = t >> 6;
    if (t == 0) sCnt = 0u;
    __syncthreads();

    // ---- Phase A: block-local selection. Thread t owns codes [32t, 32t+32)
    // (= natural chunks 2t, 2t+1). Frozen ee formula (R1-validated).
    const float4* embv = (const float4*)emb;
    float cm0 = 0.0f, cm1 = 0.0f;
    #pragma unroll
    for (int g = 0; g < 4; ++g) {
        float w[24];
        #pragma unroll
        for (int j = 0; j < 6; ++j) {
            const float4 v = embv[t * 24 + g * 6 + j];
            w[4*j] = v.x; w[4*j+1] = v.y; w[4*j+2] = v.z; w[4*j+3] = v.w;
        }
        float ee[8]; bool sf[8]; u32 tc = 0;
        #pragma unroll
        for (int i = 0; i < 8; ++i) {
            const float e0 = w[3*i], e1 = w[3*i+1], e2 = w[3*i+2];
            ee[i] = __fadd_rn(__fadd_rn(__fmul_rn(e0,e0), __fmul_rn(e1,e1)),
                              __fmul_rn(e2,e2));
            sf[i] = ee[i] > THETA;
            tc += sf[i] ? 1u : 0u;
            if (!sf[i]) { if (g < 2) cm0 = fmaxf(cm0, ee[i]); else cm1 = fmaxf(cm1, ee[i]); }
        }
        u32 incl = tc;                      // wave-inclusive scan
        #pragma unroll
        for (int o = 1; o < 64; o <<= 1) {
            const u32 v = __shfl_up(incl, o, 64);
            if (lane >= o) incl += v;
        }
        const u32 excl = incl - tc;
        u32 wb = 0;
        if (lane == 63) wb = atomicAdd(&sCnt, incl);   // one atomic per wave per group
        const u32 base = __shfl(wb, 63, 64);
        u32 r = 0;
        #pragma unroll
        for (int i = 0; i < 8; ++i) {
            if (sf[i]) {
                const u32 p = base + excl + r; ++r;
                const float e0 = w[3*i], e1 = w[3*i+1], e2 = w[3*i+2];
                if (p < CAP) {
                    sSel[p] = make_float4(e0+e0, e1+e1, e2+e2, ee[i]);
                    sOrd[p] = (u32)(t * 32 + g * 8 + i);
                } else {   // overflow (impossible stats, exact anyway): cover via cmax
                    if (g < 2) cm0 = fmaxf(cm0, ee[i]); else cm1 = fmaxf(cm1, ee[i]);
                }
            }
        }
    }
    sCmax[2*t] = cm0; sCmax[2*t + 1] = cm1;
    __syncthreads();
    const u32 cnt = sCnt;
    const u32 cap64 = (cnt + 63u) & ~63u;
    const u32 padded = cap64 < (u32)CAP ? cap64 : (u32)CAP;
    if (t < (int)(padded - cnt)) { sSel[cnt + t] = sSel[0]; sOrd[cnt + t] = sOrd[0]; }
    __syncthreads();

    // ---- Phase B: scan. Wave owns 8 rows; lane scans sel positions == lane mod 64.
    const int wrow0 = blockIdx.x * ROWS_PB + wave * RPW;
    float X0[RPW], X1[RPW], X2[RPW], XX[RPW];
    #pragma unroll
    for (int r = 0; r < RPW; ++r) {
        X0[r] = feats[3*(wrow0+r)+0];
        X1[r] = feats[3*(wrow0+r)+1];
        X2[r] = feats[3*(wrow0+r)+2];
        XX[r] = __fadd_rn(__fadd_rn(__fmul_rn(X0[r],X0[r]), __fmul_rn(X1[r],X1[r])),
                          __fmul_rn(X2[r],X2[r]));
    }
    float BD[RPW]; u32 BO[RPW];
    #pragma unroll
    for (int r = 0; r < RPW; ++r) { BD[r] = __int_as_float(0x7f800000); BO[r] = 0xffffffffu; }

    for (u32 pos = (u32)lane; pos < padded; pos += 64u) {
        const float4 E  = sSel[pos];
        const u32 orig  = sOrd[pos];
        #pragma unroll
        for (int r = 0; r < RPW; ++r) {
            const float xe2 = __fmaf_rn(X2[r], E.z, __fmaf_rn(X1[r], E.y, __fmul_rn(X0[r], E.x)));
            const float d   = __fadd_rn(__fsub_rn(XX[r], xe2), E.w);   // frozen
            const bool bt = (d < BD[r]) || (d == BD[r] && orig < BO[r]);  // exact (d,idx) lex
            if (bt) { BD[r] = d; BO[r] = orig; }
        }
    }

    u64 K[RPW];
    #pragma unroll
    for (int r = 0; r < RPW; ++r) {
        u64 k = ((u64)__float_as_uint(BD[r]) << 32) | (u64)BO[r];
        #pragma unroll
        for (int o = 1; o < 64; o <<= 1) { const u64 v = __shfl_xor(k, o, 64); if (v < k) k = v; }
        K[r] = k;
    }

    // ---- Prune check: all non-scanned codes have ee <= THETA (when cnt<=CAP).
    // Margins (validated R5): sx lower-bounds ||x||; T2 under-estimates T^2.
    const bool covered = (cnt <= (u32)CAP);
    bool anyfail = false; float T2min = 1.0e30f;
    #pragma unroll
    for (int r = 0; r < RPW; ++r) {
        const float gb = __uint_as_float((u32)(K[r] >> 32));
        const float sx = sqrtf(XX[r]) - 1e-5f;
        const float T  = sx - (sqrtf(gb + 1e-4f) + 1e-5f);
        const float T2 = (T > 0.0f) ? (T*T - 1e-5f) : -1.0e30f;
        const bool fail = !(covered && (THETA < T2));
        if (fail) { anyfail = true; T2min = fminf(T2min, T2); }
    }

    if (anyfail) {   // near-never: exact fallback over natural chunks via cmax bound
        for (int kk = 0; kk < (VOCAB/16)/4; ++kk) {
            const int q = 4*kk + (lane >> 4);
            const int c = lane & 15;
            const bool act = (sCmax[q] >= T2min);
            if (__ballot(act) == 0ull) continue;
            if (act) {
                const int code = q*16 + c;
                const float e0 = emb[3*code], e1 = emb[3*code+1], e2 = emb[3*code+2];
                const float ee = __fadd_rn(__fadd_rn(__fmul_rn(e0,e0), __fmul_rn(e1,e1)),
                                           __fmul_rn(e2,e2));
                #pragma unroll
                for (int r = 0; r < RPW; ++r) {
                    const float xe = __fmaf_rn(X2[r], e2, __fmaf_rn(X1[r], e1, __fmul_rn(X0[r], e0)));
                    const float d  = __fadd_rn(__fsub_rn(XX[r], __fadd_rn(xe, xe)), ee);
                    const u32 orig = (u32)code;
                    const bool bt = (d < BD[r]) || (d == BD[r] && orig < BO[r]);
                    if (bt) { BD[r] = d; BO[r] = orig; }
                }
            }
        }
        #pragma unroll
        for (int r = 0; r < RPW; ++r) {
            u64 k = ((u64)__float_as_uint(BD[r]) << 32) | (u64)BO[r];
            #pragma unroll
            for (int o = 1; o < 64; o <<= 1) { const u64 v = __shfl_xor(k, o, 64); if (v < k) k = v; }
            K[r] = k;
        }
    }

    // ---- Phase C: outputs (lane r emits row wrow0+r) + block loss partial.
    u64 mykey = K[0];
    #pragma unroll
    for (int r = 1; r < RPW; ++r) mykey = (lane == r) ? K[r] : mykey;

    float s = 0.0f;
    if (lane < RPW) {
        const int row = wrow0 + lane;
        const u32 idx = (u32)(mykey & 0xffffffffULL);
        const float e0 = emb[3*idx+0], e1 = emb[3*idx+1], e2 = emb[3*idx+2];
        const float fx0 = feats[3*row+0], fx1 = feats[3*row+1], fx2 = feats[3*row+2];
        out_quant[3*row+0] = __fadd_rn(fx0, __fsub_rn(e0, fx0));
        out_quant[3*row+1] = __fadd_rn(fx1, __fsub_rn(e1, fx1));
        out_quant[3*row+2] = __fadd_rn(fx2, __fsub_rn(e2, fx2));
        out_idx[row] = (float)idx;
        const float d0 = e0 - fx0, d1 = e1 - fx1, d2 = e2 - fx2;
        s = d0*d0 + d1*d1 + d2*d2;
    }
    #pragma unroll
    for (int o = 1; o < 64; o <<= 1) s += __shfl_xor(s, o, 64);
    if (lane == 0) wsum[wave] = s;
    __syncthreads();
    if (t == 0) part[blockIdx.x] = (wsum[0] + wsum[1]) + (wsum[2] + wsum[3]);
}

// ---------------------------------------------------------------------------
__global__ __launch_bounds__(GRID) void vq_loss(
    const float* __restrict__ part, float* __restrict__ out_loss)
{
    __shared__ float ws[GRID / 64];
    float s = part[threadIdx.x];
    #pragma unroll
    for (int o = 1; o < 64; o <<= 1) s += __shfl_xor(s, o, 64);
    if ((threadIdx.x & 63) == 0) ws[threadIdx.x >> 6] = s;
    __syncthreads();
    if (threadIdx.x == 0) {
        float tsum = 0.0f;
        #pragma unroll
        for (int i = 0; i < GRID / 64; ++i) tsum += ws[i];
        const float m = tsum / (float)(N_ROWS * 3);
        out_loss[0] = __fadd_rn(m, __fmul_rn(0.25f, m));
    }
}

extern "C" void kernel_launch(void* const* d_in, const int* in_sizes, int n_in,
                              void* d_out, int out_size, void* d_ws, size_t ws_size,
                              hipStream_t stream)
{
    const float* feats = (const float*)d_in[0];   // [4,4096,3] f32
    const float* emb   = (const float*)d_in[1];   // [8192,3]   f32
    float* out = (float*)d_out;
    float* part = (float*)d_ws;

    vq_main<<<GRID, THREADS, 0, stream>>>(
        feats, emb, out, out + (size_t)N_ROWS * 3, part);
    vq_loss<<<1, GRID, 0, stream>>>(part, out + (size_t)N_ROWS * 4);
}

// Round 8
// 106.627 us; speedup vs baseline: 1.1652x; 1.1652x over previous
//
#include <hip/hip_runtime.h>
#include <cstdint>

// B=4, L=4096, D=3, VOCAB=8192
#define N_ROWS   16384
#define VOCAB    8192
#define THETA    0.00226f      // select threshold: ~13% of codes above (ee ~ 4e-4*chi2_3)
#define CAP      2048          // sel capacity (expect ~1065, sigma~30 -> +32 sigma)
#define THREADS  256           // 4 waves
#define RPW      4             // rows per wave (register-resident, no spill)
#define ROWS_PB  16            // 4 waves * 4
#define GRID     (N_ROWS / ROWS_PB)   // 1024 blocks

typedef unsigned long long u64;
typedef unsigned int u32;

// d_out (floats): [0,49152) quant_ste | [49152,65536) idx | [65536] vq_loss
// d_ws: [0, GRID*4) float block partials

__global__ __launch_bounds__(THREADS, 4) void vq_main(
    const float* __restrict__ feats, const float* __restrict__ emb,
    float* __restrict__ out_quant, float* __restrict__ out_idx,
    float* __restrict__ part)
{
    __shared__ float4 sSel[CAP];   // (2e0,2e1,2e2,ee) of selected codes
    __shared__ u32    sOrd[CAP];   // original code index
    __shared__ u32    sCnt;
    __shared__ float  wsum[4];

    const int t = threadIdx.x, lane = t & 63, wave = t >> 6;
    if (t == 0) sCnt = 0u;
    __syncthreads();

    // ---- Phase A: selection, zero per-thread arrays. 32 codes/thread,
    // ballot-compaction, one LDS atomic per wave per iteration.
    for (int i = 0; i < 32; ++i) {
        const int code = t + i * THREADS;            // covers [0,8192) exactly
        const float e0 = emb[3*code+0];
        const float e1 = emb[3*code+1];
        const float e2 = emb[3*code+2];
        const float ee = __fadd_rn(__fadd_rn(__fmul_rn(e0,e0), __fmul_rn(e1,e1)),
                                   __fmul_rn(e2,e2));            // frozen
        const bool sel = ee > THETA;
        const u64 mask = __ballot(sel);
        u32 b0 = 0;
        if (lane == 0 && mask) b0 = atomicAdd(&sCnt, (u32)__popcll(mask));
        b0 = __shfl(b0, 0, 64);
        if (sel) {
            const u32 pos = b0 + (u32)__popcll(mask & ((1ull << lane) - 1ull));
            if (pos < (u32)CAP) {
                sSel[pos] = make_float4(e0+e0, e1+e1, e2+e2, ee);
                sOrd[pos] = (u32)code;
            }
        }
    }
    __syncthreads();
    const u32 cnt = sCnt;
    const bool covered = (cnt > 0u) && (cnt <= (u32)CAP);  // non-scanned => ee<=THETA
    u32 padded = 0u;
    if (covered) {
        padded = (cnt + 63u) & ~63u;
        if (t < (int)(padded - cnt)) { sSel[cnt + t] = sSel[0]; sOrd[cnt + t] = sOrd[0]; }
    }
    __syncthreads();

    // ---- Phase B: wave owns RPW rows; lane scans sel positions lane, lane+64, ...
    const int wrow0 = blockIdx.x * ROWS_PB + wave * RPW;
    float X0[RPW], X1[RPW], X2[RPW], XX[RPW];
    #pragma unroll
    for (int r = 0; r < RPW; ++r) {
        X0[r] = feats[3*(wrow0+r)+0];
        X1[r] = feats[3*(wrow0+r)+1];
        X2[r] = feats[3*(wrow0+r)+2];
        XX[r] = __fadd_rn(__fadd_rn(__fmul_rn(X0[r],X0[r]), __fmul_rn(X1[r],X1[r])),
                          __fmul_rn(X2[r],X2[r]));               // frozen
    }
    float BD[RPW]; u32 BO[RPW];
    #pragma unroll
    for (int r = 0; r < RPW; ++r) { BD[r] = __int_as_float(0x7f800000); BO[r] = 0xffffffffu; }

    for (u32 pos = (u32)lane; pos < padded; pos += 64u) {
        const float4 E = sSel[pos];
        const u32 orig = sOrd[pos];
        #pragma unroll
        for (int r = 0; r < RPW; ++r) {
            const float xe2 = __fmaf_rn(X2[r], E.z, __fmaf_rn(X1[r], E.y, __fmul_rn(X0[r], E.x)));
            const float d   = __fadd_rn(__fsub_rn(XX[r], xe2), E.w);   // frozen
            const bool bt = (d < BD[r]) || (d == BD[r] && orig < BO[r]);
            if (bt) { BD[r] = d; BO[r] = orig; }
        }
    }

    u64 K[RPW];
    #pragma unroll
    for (int r = 0; r < RPW; ++r) {
        u64 k = ((u64)__float_as_uint(BD[r]) << 32) | (u64)BO[r];
        #pragma unroll
        for (int o = 1; o < 64; o <<= 1) { const u64 v = __shfl_xor(k, o, 64); if (v < k) k = v; }
        K[r] = k;
    }

    // ---- Prune check (wave-uniform). Conservative margins, validated R5/R6.
    bool anyfail = !covered;
    #pragma unroll
    for (int r = 0; r < RPW; ++r) {
        const float gb = __uint_as_float((u32)(K[r] >> 32));
        const float sx = sqrtf(XX[r]) - 1e-5f;
        const float T  = sx - (sqrtf(gb + 1e-4f) + 1e-5f);
        const float T2 = (T > 0.0f) ? (T*T - 1e-5f) : -1.0e30f;
        if (!(THETA < T2)) anyfail = true;
    }

    if (anyfail) {   // rare: exact wave-local full scan from global
        for (int code = lane; code < VOCAB; code += 64) {
            const float e0 = emb[3*code+0];
            const float e1 = emb[3*code+1];
            const float e2 = emb[3*code+2];
            const float ee = __fadd_rn(__fadd_rn(__fmul_rn(e0,e0), __fmul_rn(e1,e1)),
                                       __fmul_rn(e2,e2));
            #pragma unroll
            for (int r = 0; r < RPW; ++r) {
                const float xe = __fmaf_rn(X2[r], e2, __fmaf_rn(X1[r], e1, __fmul_rn(X0[r], e0)));
                const float d  = __fadd_rn(__fsub_rn(XX[r], __fadd_rn(xe, xe)), ee);  // frozen
                const u32 orig = (u32)code;
                const bool bt = (d < BD[r]) || (d == BD[r] && orig < BO[r]);
                if (bt) { BD[r] = d; BO[r] = orig; }
            }
        }
        #pragma unroll
        for (int r = 0; r < RPW; ++r) {
            u64 k = ((u64)__float_as_uint(BD[r]) << 32) | (u64)BO[r];
            #pragma unroll
            for (int o = 1; o < 64; o <<= 1) { const u64 v = __shfl_xor(k, o, 64); if (v < k) k = v; }
            K[r] = k;
        }
    }

    // ---- Phase C: lane r emits row wrow0+r; block loss partial.
    u64 mykey = K[0];
    #pragma unroll
    for (int r = 1; r < RPW; ++r) mykey = (lane == r) ? K[r] : mykey;

    float s = 0.0f;
    if (lane < RPW) {
        const int row = wrow0 + lane;
        const u32 idx = (u32)(mykey & 0xffffffffULL);
        const float e0 = emb[3*idx+0], e1 = emb[3*idx+1], e2 = emb[3*idx+2];
        const float fx0 = feats[3*row+0], fx1 = feats[3*row+1], fx2 = feats[3*row+2];
        out_quant[3*row+0] = __fadd_rn(fx0, __fsub_rn(e0, fx0));
        out_quant[3*row+1] = __fadd_rn(fx1, __fsub_rn(e1, fx1));
        out_quant[3*row+2] = __fadd_rn(fx2, __fsub_rn(e2, fx2));
        out_idx[row] = (float)idx;
        const float d0 = e0 - fx0, d1 = e1 - fx1, d2 = e2 - fx2;
        s = d0*d0 + d1*d1 + d2*d2;
    }
    #pragma unroll
    for (int o = 1; o < 64; o <<= 1) s += __shfl_xor(s, o, 64);
    if (lane == 0) wsum[wave] = s;
    __syncthreads();
    if (t == 0) part[blockIdx.x] = (wsum[0] + wsum[1]) + (wsum[2] + wsum[3]);
}

// ---------------------------------------------------------------------------
__global__ __launch_bounds__(1024) void vq_loss(
    const float* __restrict__ part, float* __restrict__ out_loss)
{
    __shared__ float ws[16];
    const int t = threadIdx.x, lane = t & 63, wave = t >> 6;
    float s = part[t];
    #pragma unroll
    for (int o = 1; o < 64; o <<= 1) s += __shfl_xor(s, o, 64);
    if (lane == 0) ws[wave] = s;
    __syncthreads();
    if (t == 0) {
        float S = 0.0f;
        #pragma unroll
        for (int i = 0; i < 16; ++i) S += ws[i];
        const float m = S / (float)(N_ROWS * 3);
        out_loss[0] = __fadd_rn(m, __fmul_rn(0.25f, m));
    }
}

extern "C" void kernel_launch(void* const* d_in, const int* in_sizes, int n_in,
                              void* d_out, int out_size, void* d_ws, size_t ws_size,
                              hipStream_t stream)
{
    const float* feats = (const float*)d_in[0];   // [4,4096,3] f32
    const float* emb   = (const float*)d_in[1];   // [8192,3]   f32
    float* out = (float*)d_out;
    float* part = (float*)d_ws;

    vq_main<<<GRID, THREADS, 0, stream>>>(
        feats, emb, out, out + (size_t)N_ROWS * 3, part);
    vq_loss<<<1, 1024, 0, stream>>>(part, out + (size_t)N_ROWS * 4);
}